// Round 3
// baseline (712.387 us; speedup 1.0000x reference)
//
#include <hip/hip_runtime.h>
#include <cstdint>
#include <cstddef>

#define BM 128
#define BN 128
#define BK 64

typedef float f32x4 __attribute__((ext_vector_type(4)));
typedef __bf16 bf16x8 __attribute__((ext_vector_type(8)));

__device__ __forceinline__ unsigned short f2bf(float f) {
    unsigned int u = __float_as_uint(f);
    u += 0x7fffu + ((u >> 16) & 1u);   // round-to-nearest-even
    return (unsigned short)(u >> 16);
}

__device__ __forceinline__ void async_copy16(const void* g, void* l) {
    __builtin_amdgcn_global_load_lds(
        (__attribute__((address_space(1))) void*)(g),
        (__attribute__((address_space(3))) void*)(l), 16, 0, 0);
}

// ---------------- fused prep: cast x, dequant L, transposed-dequant R -------
// unit u: [0, NX)            -> xb[u*8..]      = bf16(x)
//         [NX, NX+NL)        -> Ld[(u-NX)*8..] = bf16(lv*ls)
//         [NX+NL, NX+NL+NR)  -> RdT[c, r]      = bf16(rv*rs)  (scatter, L2-absorbed)
__global__ void prep_kernel(const float* __restrict__ x, unsigned short* __restrict__ xb,
                            const int* __restrict__ lv, const float* __restrict__ ls,
                            unsigned short* __restrict__ Ld,
                            const int* __restrict__ rv, const float* __restrict__ rs,
                            unsigned short* __restrict__ RdT,
                            int NX, int NL, int NR) {
    int u = blockIdx.x * blockDim.x + threadIdx.x;
    if (u < NX) {
        const float4* xv = (const float4*)x;
        float4 a = xv[2 * (size_t)u];
        float4 b = xv[2 * (size_t)u + 1];
        union { unsigned short s[8]; uint4 v; } r;
        r.s[0] = f2bf(a.x); r.s[1] = f2bf(a.y); r.s[2] = f2bf(a.z); r.s[3] = f2bf(a.w);
        r.s[4] = f2bf(b.x); r.s[5] = f2bf(b.y); r.s[6] = f2bf(b.z); r.s[7] = f2bf(b.w);
        ((uint4*)xb)[u] = r.v;
    } else if (u < NX + NL) {
        int i = u - NX;                 // L: [4096, 256], group 128 -> 2 scales/row
        int e = i * 8;
        int row = e >> 8, col = e & 255;
        float sc = ls[row * 2 + (col >> 7)];
        int4 a = ((const int4*)lv)[2 * (size_t)i];
        int4 b = ((const int4*)lv)[2 * (size_t)i + 1];
        union { unsigned short s[8]; uint4 v; } r;
        r.s[0] = f2bf(a.x * sc); r.s[1] = f2bf(a.y * sc);
        r.s[2] = f2bf(a.z * sc); r.s[3] = f2bf(a.w * sc);
        r.s[4] = f2bf(b.x * sc); r.s[5] = f2bf(b.y * sc);
        r.s[6] = f2bf(b.z * sc); r.s[7] = f2bf(b.w * sc);
        ((uint4*)Ld)[i] = r.v;
    } else if (u < NX + NL + NR) {
        int i = u - NX - NL;            // R: [256, 4096] -> RdT [4096, 256]
        int e = i * 8;
        int row = e >> 12, col = e & 4095;
        float sc = rs[row * 32 + (col >> 7)];
        int4 a = ((const int4*)rv)[2 * (size_t)i];
        int4 b = ((const int4*)rv)[2 * (size_t)i + 1];
        int c[8] = {a.x, a.y, a.z, a.w, b.x, b.y, b.z, b.w};
        #pragma unroll
        for (int j = 0; j < 8; ++j)
            RdT[(size_t)(col + j) * 256 + row] = f2bf(c[j] * sc);
    }
}

// ---------------- GEMM: C[M,N] = A*B^T, optional fused Q-dequant add --------
// 128x128 tile, BK=64, 4 waves (2x2, 64x64 each), 16x16x32 bf16 MFMA,
// global_load_lds width-16 staging, XOR-swizzled LDS (chunk' = chunk ^ (row&7))
// -> zero bank conflicts (R2 verified).
__global__ void __launch_bounds__(256)
gemm_bt_kernel(const __bf16* __restrict__ A, int lda, int ksteps,
               const __bf16* __restrict__ B,
               const float* __restrict__ bias,
               const int* __restrict__ qv,       // optional: codes [M, ldo]
               const float* __restrict__ qsc,    // optional: scales [M, ldo/128]
               float* __restrict__ outf,
               unsigned short* __restrict__ outb,
               int ldo) {
    __shared__ __bf16 As[BM * BK];   // 16 KB
    __shared__ __bf16 Bs[BN * BK];   // 16 KB

    const int tid  = threadIdx.x;
    const int lane = tid & 63;
    const int wave = tid >> 6;
    const int wm = (wave >> 1) * 64;
    const int wn = (wave & 1) * 64;
    const int mBase = blockIdx.y * BM;
    const int nBase = blockIdx.x * BN;
    const int lrow = lane >> 3;                          // 0..7 row in 8-row chunk
    const int lcol = (((lane & 7) ^ lrow) & 7) * 8;      // swizzled chunk in 64-row

    f32x4 acc[4][4] = {};

    for (int kt = 0; kt < ksteps; ++kt) {
        const int k0 = kt * BK;
        #pragma unroll
        for (int r = 0; r < 4; ++r) {
            const int chunk = wave * 4 + r;          // 0..15
            const int row = chunk * 8 + lrow;        // 0..127
            async_copy16(A + (size_t)(mBase + row) * lda + (k0 + lcol),
                         &As[chunk * 512]);
            async_copy16(B + (size_t)(nBase + row) * lda + (k0 + lcol),
                         &Bs[chunk * 512]);
        }
        __syncthreads();

        #pragma unroll
        for (int ks = 0; ks < 2; ++ks) {
            const int kofs = ks * 32 + (lane >> 4) * 8;
            const int swz = kofs >> 3;
            bf16x8 af[4], bfr[4];
            #pragma unroll
            for (int i = 0; i < 4; ++i) {
                const int m = wm + i * 16 + (lane & 15);
                af[i] = *(const bf16x8*)&As[m * BK + (((swz ^ m) & 7) << 3)];
            }
            #pragma unroll
            for (int j = 0; j < 4; ++j) {
                const int n = wn + j * 16 + (lane & 15);
                bfr[j] = *(const bf16x8*)&Bs[n * BK + (((swz ^ n) & 7) << 3)];
            }
            #pragma unroll
            for (int i = 0; i < 4; ++i)
                #pragma unroll
                for (int j = 0; j < 4; ++j)
                    acc[i][j] = __builtin_amdgcn_mfma_f32_16x16x32_bf16(
                        af[i], bfr[j], acc[i][j], 0, 0, 0);
        }
        __syncthreads();
    }

    // epilogue: C/D layout col = lane&15, row = (lane>>4)*4 + reg
    const int cn = lane & 15;
    const int rg = (lane >> 4) * 4;
    if (outf) {
        #pragma unroll
        for (int j = 0; j < 4; ++j) {
            const int o = nBase + wn + j * 16 + cn;
            const float bv = bias[o];
            #pragma unroll
            for (int i = 0; i < 4; ++i) {
                const int t0 = mBase + wm + i * 16 + rg;
                #pragma unroll
                for (int r = 0; r < 4; ++r)
                    outf[(size_t)(t0 + r) * ldo + o] = acc[i][j][r] + bv;
            }
        }
    } else {
        const int sld = ldo >> 7;   // scales per row
        #pragma unroll
        for (int j = 0; j < 4; ++j) {
            const int o = nBase + wn + j * 16 + cn;
            #pragma unroll
            for (int i = 0; i < 4; ++i) {
                const int t0 = mBase + wm + i * 16 + rg;
                #pragma unroll
                for (int r = 0; r < 4; ++r) {
                    float v = acc[i][j][r];
                    if (qv)
                        v += (float)qv[(size_t)(t0 + r) * ldo + o] *
                             qsc[(size_t)(t0 + r) * sld + (o >> 7)];
                    outb[(size_t)(t0 + r) * ldo + o] = f2bf(v);
                }
            }
        }
    }
}

extern "C" void kernel_launch(void* const* d_in, const int* in_sizes, int n_in,
                              void* d_out, int out_size, void* d_ws, size_t ws_size,
                              hipStream_t stream) {
    const float* x    = (const float*)d_in[0];
    const int*   qv   = (const int*)d_in[1];
    const float* qs   = (const float*)d_in[2];
    const int*   lv   = (const int*)d_in[3];
    const float* ls   = (const float*)d_in[4];
    const int*   rv   = (const int*)d_in[5];
    const float* rs   = (const float*)d_in[6];
    const float* bias = (const float*)d_in[7];
    float* out = (float*)d_out;

    const int T = 8192, DI = 4096, DO = 4096, R = 256;

    // workspace layout (all 16B-aligned; total 100 MiB)
    char* ws = (char*)d_ws;
    unsigned short* xb  = (unsigned short*)(ws);               // 8192x4096 bf16 = 64 MiB
    unsigned short* Wd  = (unsigned short*)(ws + 67108864);    // 4096x4096 bf16 = 32 MiB
    unsigned short* Ld  = (unsigned short*)(ws + 100663296);   // 4096x 256 bf16 =  2 MiB
    unsigned short* RdT = (unsigned short*)(ws + 102760448);   // 4096x 256 bf16 =  2 MiB

    {   // fused prep: x-cast + L-dequant + R-transposed-dequant
        int NX = T * DI / 8, NL = DO * R / 8, NR = R * DI / 8;
        int n = NX + NL + NR;
        prep_kernel<<<(n + 255) / 256, 256, 0, stream>>>(
            x, xb, lv, ls, Ld, rv, rs, RdT, NX, NL, NR);
    }
    {   // W-gemm: Wd[o,i] = bf16( Ld @ RdT^T + dequant(Q) )   [4096,4096], K=256
        dim3 g(DI / BN, DO / BM);
        gemm_bt_kernel<<<g, 256, 0, stream>>>(
            (const __bf16*)Ld, R, R / BK, (const __bf16*)RdT,
            nullptr, qv, qs, nullptr, Wd, DI);
    }
    {   // main gemm: out[t,o] = xb @ Wd^T + bias   [8192,4096], K=4096
        dim3 g(DO / BN, T / BM);
        gemm_bt_kernel<<<g, 256, 0, stream>>>(
            (const __bf16*)xb, DI, DI / BK, (const __bf16*)Wd,
            bias, nullptr, nullptr, out, nullptr, DO);
    }
}